// Round 1
// baseline (240.266 us; speedup 1.0000x reference)
//
#include <hip/hip_runtime.h>
#include <math.h>

#define Bn 16
#define Cn 3
#define Hn 512
#define Wn 512
#define HWn (Hn*Wn)          // 262144
#define CHWn (Cn*HWn)        // 786432
#define Rr 8                 // rows per thread strip

__device__ __forceinline__ float clamp01(float x) {
    return fminf(fmaxf(x, 0.0f), 1.0f);
}

// ---------------------------------------------------------------------------
// Kernel 1: per-batch sum of gray(input_ir), gray = .2989 R + .587 G + .114 B
// grid = (32, B), block = 256. Each block sums 8192 pixels of one batch.
// Result accumulated in ws[b] (b = 0..15).
// ---------------------------------------------------------------------------
__global__ __launch_bounds__(256) void gray_mean_kernel(
        const float* __restrict__ ir, float* __restrict__ ws)
{
    const int b = blockIdx.y;
    const int tid = threadIdx.x;
    const float* base = ir + (size_t)b * CHWn;

    float sr = 0.f, sg = 0.f, sb = 0.f;
#pragma unroll
    for (int k = 0; k < 8; ++k) {
        size_t px = (size_t)blockIdx.x * 8192 + (size_t)(k * 256 + tid) * 4;
        float4 r4 = *(const float4*)(base + px);
        float4 g4 = *(const float4*)(base + HWn + px);
        float4 b4 = *(const float4*)(base + 2 * HWn + px);
        sr += (r4.x + r4.y) + (r4.z + r4.w);
        sg += (g4.x + g4.y) + (g4.z + g4.w);
        sb += (b4.x + b4.y) + (b4.z + b4.w);
    }
    float s = 0.2989f * sr + 0.587f * sg + 0.114f * sb;

#pragma unroll
    for (int off = 32; off; off >>= 1) s += __shfl_down(s, off, 64);

    __shared__ float red[4];
    if ((tid & 63) == 0) red[tid >> 6] = s;
    __syncthreads();
    if (tid == 0) atomicAdd(&ws[b], (red[0] + red[1]) + (red[2] + red[3]));
}

// ---------------------------------------------------------------------------
// Kernel 2: main fused kernel.
// grid = (Hn/(2*Rr), B) = (32,16), block = 256.
// Thread layout: tx = tid&127 -> x0 = 4*tx (covers all 512 cols),
//                sy = tid>>7  -> two Rr-row strips per block.
// Accumulates into ws[16..20]: con, gx, gy, cr, cb sums.
// ---------------------------------------------------------------------------
__global__ __launch_bounds__(256) void fusion_main_kernel(
        const float* __restrict__ vis, const float* __restrict__ ir,
        const float* __restrict__ outp, const float* __restrict__ mask,
        float* __restrict__ ws)
{
    const int tid = threadIdx.x;
    const int tx = tid & 127;
    const int sy = tid >> 7;
    const int b  = blockIdx.y;
    const int y0 = (blockIdx.x * 2 + sy) * Rr;
    const int x0 = tx * 4;

    const float mean_b = ws[b] * (1.0f / (float)HWn);
    const float moff = 0.8f * mean_b;   // R_ir = clamp01(1.8*ir - moff)

    const size_t bb = (size_t)b * CHWn;
    const float* pv = vis  + bb;
    const float* pi = ir   + bb;
    const float* po = outp + bb;
    const float* pm = mask + bb;

    float conA = 0.f, gxA = 0.f, gyA = 0.f;

    // ---------------- per-channel sobel + intensity pass ----------------
    for (int c = 0; c < 3; ++c) {
        const float* v_ = pv + (size_t)c * HWn;
        const float* i_ = pi + (size_t)c * HWn;
        const float* o_ = po + (size_t)c * HWn;
        const float* m_ = pm + (size_t)c * HWn;

        // sliding window: slot 0 = row y-1, 1 = row y, 2 = row y+1
        // 6 columns: x0-1 .. x0+4
        float wf[3][6], wv[3][6], wi[3][6];

        auto load_row = [&](int y, int s) {
            if ((unsigned)y < (unsigned)Hn) {
                size_t o = (size_t)y * Wn + x0;
                float4 o4 = *(const float4*)(o_ + o);
                float4 m4 = *(const float4*)(m_ + o);
                float4 v4 = *(const float4*)(v_ + o);
                float4 i4 = *(const float4*)(i_ + o);
                float oL = 0.f, mL = 0.f, vL = 0.f, iL = 0.f;
                float oR = 0.f, mR = 0.f, vR = 0.f, iR = 0.f;
                if (x0 > 0)      { oL = o_[o - 1]; mL = m_[o - 1]; vL = v_[o - 1]; iL = i_[o - 1]; }
                if (x0 + 4 < Wn) { oR = o_[o + 4]; mR = m_[o + 4]; vR = v_[o + 4]; iR = i_[o + 4]; }

                wf[s][0] = oL * mL;     wf[s][1] = o4.x * m4.x;
                wf[s][2] = o4.y * m4.y; wf[s][3] = o4.z * m4.z;
                wf[s][4] = o4.w * m4.w; wf[s][5] = oR * mR;

                wv[s][0] = clamp01(sqrtf(vL));   wv[s][1] = clamp01(sqrtf(v4.x));
                wv[s][2] = clamp01(sqrtf(v4.y)); wv[s][3] = clamp01(sqrtf(v4.z));
                wv[s][4] = clamp01(sqrtf(v4.w)); wv[s][5] = clamp01(sqrtf(vR));

                wi[s][0] = clamp01(fmaf(1.8f, iL,   -moff));
                wi[s][1] = clamp01(fmaf(1.8f, i4.x, -moff));
                wi[s][2] = clamp01(fmaf(1.8f, i4.y, -moff));
                wi[s][3] = clamp01(fmaf(1.8f, i4.z, -moff));
                wi[s][4] = clamp01(fmaf(1.8f, i4.w, -moff));
                wi[s][5] = clamp01(fmaf(1.8f, iR,   -moff));
                // note: OOB columns hold source 0 -> derived value is exactly 0
                // (fuse: 0*0, rvis: sqrt(0), rir: clamp01(-moff) with moff>=0),
                // matching the conv's zero padding of the derived planes.
                if (x0 == 0)       { wf[s][0] = 0.f; wv[s][0] = 0.f; wi[s][0] = 0.f; }
                if (x0 + 4 >= Wn)  { wf[s][5] = 0.f; wv[s][5] = 0.f; wi[s][5] = 0.f; }
            } else {
#pragma unroll
                for (int k = 0; k < 6; ++k) { wf[s][k] = 0.f; wv[s][k] = 0.f; wi[s][k] = 0.f; }
            }
        };

        load_row(y0 - 1, 0);
        load_row(y0,     1);

        for (int yy = 0; yy < Rr; ++yy) {
            load_row(y0 + yy + 1, 2);

#pragma unroll
            for (int j = 0; j < 4; ++j) {
                // cross-correlation (XLA conv): no kernel flip.
                // gx = (A[x+1]-A[x-1]) + 2(B[x+1]-B[x-1]) + (C[x+1]-C[x-1])
                // gy = (A[x-1]+2A[x]+A[x+1]) - (C[x-1]+2C[x]+C[x+1])
                float gxf = (wf[0][j+2] - wf[0][j]) + 2.f * (wf[1][j+2] - wf[1][j]) + (wf[2][j+2] - wf[2][j]);
                float gyf = (wf[0][j] + 2.f * wf[0][j+1] + wf[0][j+2]) - (wf[2][j] + 2.f * wf[2][j+1] + wf[2][j+2]);

                float gxv = (wv[0][j+2] - wv[0][j]) + 2.f * (wv[1][j+2] - wv[1][j]) + (wv[2][j+2] - wv[2][j]);
                float gyv = (wv[0][j] + 2.f * wv[0][j+1] + wv[0][j+2]) - (wv[2][j] + 2.f * wv[2][j+1] + wv[2][j+2]);

                float gxi = (wi[0][j+2] - wi[0][j]) + 2.f * (wi[1][j+2] - wi[1][j]) + (wi[2][j+2] - wi[2][j]);
                float gyi = (wi[0][j] + 2.f * wi[0][j+1] + wi[0][j+2]) - (wi[2][j] + 2.f * wi[2][j+1] + wi[2][j+2]);

                gxA  += fabsf(gxf - fmaxf(gxv, gxi));
                gyA  += fabsf(gyf - fmaxf(gyv, gyi));
                conA += fabsf(wf[1][j+1] - fmaxf(wv[1][j+1], wi[1][j+1]));
            }

#pragma unroll
            for (int k = 0; k < 6; ++k) {
                wf[0][k] = wf[1][k]; wf[1][k] = wf[2][k];
                wv[0][k] = wv[1][k]; wv[1][k] = wv[2][k];
                wi[0][k] = wi[1][k]; wi[1][k] = wi[2][k];
            }
        }
    }

    // ---------------- color pass (center pixels, all 3 channels) ----------------
    float crA = 0.f, cbA = 0.f;
    {
        auto px = [&](float fr, float fg, float fb, float vr, float vg, float vb) {
            float fY = 0.299f * fr + 0.587f * fg + 0.114f * fb;
            float vY = 0.299f * vr + 0.587f * vg + 0.114f * vb;
            float crf = (fr - fY) * 0.713f, crv = (vr - vY) * 0.713f;
            float cbf = (fb - fY) * 0.564f, cbv = (vb - vY) * 0.564f;
            crA += fabsf(crf - crv);
            cbA += fabsf(cbf - cbv);
        };
        for (int y = y0; y < y0 + Rr; ++y) {
            size_t o = (size_t)y * Wn + x0;
            float4 oR = *(const float4*)(po + o);
            float4 oG = *(const float4*)(po + HWn + o);
            float4 oB = *(const float4*)(po + 2 * HWn + o);
            float4 mR = *(const float4*)(pm + o);
            float4 mG = *(const float4*)(pm + HWn + o);
            float4 mB = *(const float4*)(pm + 2 * HWn + o);
            float4 vR = *(const float4*)(pv + o);
            float4 vG = *(const float4*)(pv + HWn + o);
            float4 vB = *(const float4*)(pv + 2 * HWn + o);
            px(oR.x * mR.x, oG.x * mG.x, oB.x * mB.x,
               clamp01(sqrtf(vR.x)), clamp01(sqrtf(vG.x)), clamp01(sqrtf(vB.x)));
            px(oR.y * mR.y, oG.y * mG.y, oB.y * mB.y,
               clamp01(sqrtf(vR.y)), clamp01(sqrtf(vG.y)), clamp01(sqrtf(vB.y)));
            px(oR.z * mR.z, oG.z * mG.z, oB.z * mB.z,
               clamp01(sqrtf(vR.z)), clamp01(sqrtf(vG.z)), clamp01(sqrtf(vB.z)));
            px(oR.w * mR.w, oG.w * mG.w, oB.w * mB.w,
               clamp01(sqrtf(vR.w)), clamp01(sqrtf(vG.w)), clamp01(sqrtf(vB.w)));
        }
    }

    // ---------------- block reduction + atomics ----------------
    auto wred = [](float x) {
#pragma unroll
        for (int off = 32; off; off >>= 1) x += __shfl_down(x, off, 64);
        return x;
    };
    conA = wred(conA); gxA = wred(gxA); gyA = wred(gyA);
    crA  = wred(crA);  cbA = wred(cbA);

    __shared__ float red[5][4];
    const int lane = tid & 63, w = tid >> 6;
    if (lane == 0) {
        red[0][w] = conA; red[1][w] = gxA; red[2][w] = gyA;
        red[3][w] = crA;  red[4][w] = cbA;
    }
    __syncthreads();
    if (tid < 5) {
        float s = (red[tid][0] + red[tid][1]) + (red[tid][2] + red[tid][3]);
        atomicAdd(&ws[16 + tid], s);
    }
}

// ---------------------------------------------------------------------------
// Kernel 3: finalize scalar loss.
// loss = 0.5*con + 0.2*(0.5*gx + 0.5*gy) + (cb + cr)
// con/gx/gy means over B*3*H*W; cr/cb means over B*1*H*W.
// ---------------------------------------------------------------------------
__global__ void finalize_kernel(const float* __restrict__ ws, float* __restrict__ out)
{
    if (threadIdx.x == 0 && blockIdx.x == 0) {
        const float invN3 = 1.0f / (float)((size_t)Bn * Cn * HWn);
        const float invN1 = 1.0f / (float)((size_t)Bn * HWn);
        float con = ws[16] * invN3;
        float gx  = ws[17] * invN3;
        float gy  = ws[18] * invN3;
        float cr  = ws[19] * invN1;
        float cb  = ws[20] * invN1;
        out[0] = 0.5f * con + 0.2f * (0.5f * gx + 0.5f * gy) + (cb + cr);
    }
}

extern "C" void kernel_launch(void* const* d_in, const int* in_sizes, int n_in,
                              void* d_out, int out_size, void* d_ws, size_t ws_size,
                              hipStream_t stream)
{
    const float* vis = (const float*)d_in[0];
    const float* ir  = (const float*)d_in[1];
    const float* out = (const float*)d_in[2];
    const float* msk = (const float*)d_in[3];
    float* ws = (float*)d_ws;

    // ws[0..15] = per-batch gray sums; ws[16..20] = loss accumulators
    hipMemsetAsync(ws, 0, 32 * sizeof(float), stream);

    gray_mean_kernel<<<dim3(32, Bn), 256, 0, stream>>>(ir, ws);
    fusion_main_kernel<<<dim3(Hn / (2 * Rr), Bn), 256, 0, stream>>>(vis, ir, out, msk, ws);
    finalize_kernel<<<1, 64, 0, stream>>>(ws, (float*)d_out);
}